// Round 3
// baseline (544.884 us; speedup 1.0000x reference)
//
#include <hip/hip_runtime.h>
#include <hip/hip_bf16.h>
#include <math.h>

// Problem constants
#define BB 8
#define HH 16
#define DD 1024
#define HD 64
#define PAST 8192
#define PAIRS (BB*HH)        // 128
#define CHUNKS 8
#define CHUNK (PAST/CHUNKS)  // 1024
#define PART_STRIDE 66       // m, l, o[64]

// ---------------- Kernel A: QKV projection (GEMV, wave per output elem) ----
// qkv[mat][b][j] = sum_d x[b][d] * W[j][d] + bias[j]   (fp32)
__global__ __launch_bounds__(256) void qkv_kernel(
    const float* __restrict__ x,
    const float* __restrict__ Wq, const float* __restrict__ bq,
    const float* __restrict__ Wk, const float* __restrict__ bk,
    const float* __restrict__ Wv, const float* __restrict__ bv,
    float* __restrict__ qkv)
{
    int wid  = blockIdx.x * 4 + (threadIdx.x >> 6);   // [0, 24576)
    int lane = threadIdx.x & 63;
    int mat  = wid >> 13;            // 0=q 1=k 2=v
    int rem  = wid & 8191;
    int b    = rem >> 10;
    int j    = rem & 1023;
    const float* W    = (mat == 0) ? Wq : ((mat == 1) ? Wk : Wv);
    const float* bias = (mat == 0) ? bq : ((mat == 1) ? bk : bv);
    const float* xr = x + b * DD;
    const float* wr = W + (size_t)j * DD;
    float sum = 0.f;
    #pragma unroll
    for (int t = 0; t < 4; ++t) {
        float4 w4 = *(const float4*)(wr + t * 256 + lane * 4);
        float4 x4 = *(const float4*)(xr + t * 256 + lane * 4);
        sum = fmaf(x4.x, w4.x, sum);
        sum = fmaf(x4.y, w4.y, sum);
        sum = fmaf(x4.z, w4.z, sum);
        sum = fmaf(x4.w, w4.w, sum);
    }
    #pragma unroll
    for (int m = 32; m; m >>= 1) sum += __shfl_xor(sum, m);
    if (lane == 0)
        qkv[mat * (BB * DD) + b * DD + j] = sum + bias[j];
}

// ---------------- Kernel B: RoPE (pos = PAST), in-place on q,k -------------
__global__ __launch_bounds__(256) void rope_kernel(float* __restrict__ qkv)
{
    int tid = blockIdx.x * blockDim.x + threadIdx.x;   // [0, 4096)
    if (tid >= PAIRS * (HD / 2)) return;
    int i  = tid & 31;          // freq index [0,32)
    int bh = tid >> 5;          // pair [0,128)
    // Mimic JAX: inv_freq and ang computed/rounded in fp32, then exact trig.
    float invf = (float)pow(10000.0, -(double)i / 32.0);
    float angf = (float)PAST * invf;
    double ang = (double)angf;
    float c = (float)cos(ang), s = (float)sin(ang);
    float* q = qkv + bh * HD;
    float* k = qkv + BB * DD + bh * HD;
    float q0 = q[i], q1 = q[i + 32];
    q[i]      = q0 * c - q1 * s;
    q[i + 32] = q1 * c + q0 * s;
    float k0 = k[i], k1 = k[i + 32];
    k[i]      = k0 * c - k1 * s;
    k[i + 32] = k1 * c + k0 * s;
}

// ---------------- Kernel C: flash-decode partials over past KV -------------
// grid = PAIRS*CHUNKS blocks, 256 threads (4 waves). Wave handles 8 keys/iter:
// lane = g*8 + c where g = key-in-group (lane>>3), c = dim slice (lane&7)*8.
__global__ __launch_bounds__(256) void attn_part_kernel(
    const float* __restrict__ past_k, const float* __restrict__ past_v,
    const float* __restrict__ qkv, float* __restrict__ part)
{
    int pair  = blockIdx.x >> 3;
    int chunk = blockIdx.x & 7;
    int wave  = threadIdx.x >> 6;
    int lane  = threadIdx.x & 63;
    int g     = lane >> 3;          // key group 0..7
    int sl    = (lane & 7) * 8;     // dim slice start

    const float* q = qkv + pair * HD;
    float ql[8];
    #pragma unroll
    for (int t = 0; t < 8; ++t) ql[t] = q[sl + t] * 0.125f;  // 1/sqrt(64)

    const float* kbase = past_k + ((size_t)pair * PAST + (size_t)chunk * CHUNK) * HD;
    const float* vbase = past_v + ((size_t)pair * PAST + (size_t)chunk * CHUNK) * HD;

    float m_run = -1e30f, l_run = 0.f;
    float acc[8];
    #pragma unroll
    for (int t = 0; t < 8; ++t) acc[t] = 0.f;

    for (int i = 0; i < CHUNK / 32; ++i) {       // 32 iters
        int key = i * 32 + wave * 8 + g;
        const float* kp = kbase + (size_t)key * HD + sl;
        const float* vp = vbase + (size_t)key * HD + sl;
        float4 k0 = *(const float4*)(kp);
        float4 k1 = *(const float4*)(kp + 4);
        float4 v0 = *(const float4*)(vp);
        float4 v1 = *(const float4*)(vp + 4);
        float s = 0.f;
        s = fmaf(ql[0], k0.x, s); s = fmaf(ql[1], k0.y, s);
        s = fmaf(ql[2], k0.z, s); s = fmaf(ql[3], k0.w, s);
        s = fmaf(ql[4], k1.x, s); s = fmaf(ql[5], k1.y, s);
        s = fmaf(ql[6], k1.z, s); s = fmaf(ql[7], k1.w, s);
        // reduce dims within group of 8 lanes -> score replicated in group
        s += __shfl_xor(s, 1); s += __shfl_xor(s, 2); s += __shfl_xor(s, 4);
        // wave-wide max of the 8 group scores
        float mt = s;
        mt = fmaxf(mt, __shfl_xor(mt, 8));
        mt = fmaxf(mt, __shfl_xor(mt, 16));
        mt = fmaxf(mt, __shfl_xor(mt, 32));
        float m_new = fmaxf(m_run, mt);
        float corr  = __expf(m_run - m_new);
        float p     = __expf(s - m_new);
        float psum  = p;
        psum += __shfl_xor(psum, 8); psum += __shfl_xor(psum, 16); psum += __shfl_xor(psum, 32);
        l_run = l_run * corr + psum;
        m_run = m_new;
        acc[0] = fmaf(acc[0], corr, p * v0.x);
        acc[1] = fmaf(acc[1], corr, p * v0.y);
        acc[2] = fmaf(acc[2], corr, p * v0.z);
        acc[3] = fmaf(acc[3], corr, p * v0.w);
        acc[4] = fmaf(acc[4], corr, p * v1.x);
        acc[5] = fmaf(acc[5], corr, p * v1.y);
        acc[6] = fmaf(acc[6], corr, p * v1.z);
        acc[7] = fmaf(acc[7], corr, p * v1.w);
    }
    // merge 8 key-groups (same dim slice lives at lanes with equal lane%8)
    #pragma unroll
    for (int t = 0; t < 8; ++t) {
        acc[t] += __shfl_xor(acc[t], 8);
        acc[t] += __shfl_xor(acc[t], 16);
        acc[t] += __shfl_xor(acc[t], 32);
    }
    // merge 4 waves via LDS
    __shared__ float s_o[4][64];
    __shared__ float s_m[4], s_l[4];
    if (lane < 8) {
        #pragma unroll
        for (int t = 0; t < 8; ++t) s_o[wave][lane * 8 + t] = acc[t];
    }
    if (lane == 0) { s_m[wave] = m_run; s_l[wave] = l_run; }
    __syncthreads();
    if (threadIdx.x < 64) {
        int d = threadIdx.x;
        float m = fmaxf(fmaxf(s_m[0], s_m[1]), fmaxf(s_m[2], s_m[3]));
        float l = 0.f, o = 0.f;
        #pragma unroll
        for (int w = 0; w < 4; ++w) {
            float e = __expf(s_m[w] - m);
            l += s_l[w] * e;
            o += s_o[w][d] * e;
        }
        float* pp = part + (size_t)blockIdx.x * PART_STRIDE;
        pp[2 + d] = o;
        if (d == 0) { pp[0] = m; pp[1] = l; }
    }
}

// ---------------- Kernel D: merge partials + new-token key/value -----------
__global__ __launch_bounds__(64) void attn_reduce_kernel(
    const float* __restrict__ part, const float* __restrict__ qkv,
    float* __restrict__ attn)
{
    int pair = blockIdx.x;
    int d    = threadIdx.x;
    const float* q  = qkv + pair * HD;
    const float* kn = qkv + BB * DD + pair * HD;
    const float* vn = qkv + 2 * BB * DD + pair * HD;
    // new-token score
    float s = q[d] * kn[d];
    #pragma unroll
    for (int m = 32; m; m >>= 1) s += __shfl_xor(s, m);
    s *= 0.125f;
    const float* pp = part + (size_t)pair * CHUNKS * PART_STRIDE;
    float m = s;
    for (int c = 0; c < CHUNKS; ++c) m = fmaxf(m, pp[c * PART_STRIDE]);
    float en = __expf(s - m);
    float l = en;             // new token contributes l = exp(s-m) * 1
    float o = en * vn[d];
    for (int c = 0; c < CHUNKS; ++c) {
        float e = __expf(pp[c * PART_STRIDE] - m);
        l += pp[c * PART_STRIDE + 1] * e;
        o += pp[c * PART_STRIDE + 2 + d] * e;
    }
    attn[pair * HD + d] = o / l;
}

// ---------------- Kernel E: output projection (fp32 out) -------------------
__global__ __launch_bounds__(256) void oproj_kernel(
    const float* __restrict__ attn, const float* __restrict__ Wo,
    const float* __restrict__ bo, float* __restrict__ out)
{
    int wid  = blockIdx.x * 4 + (threadIdx.x >> 6);   // [0, 8192)
    int lane = threadIdx.x & 63;
    int b = wid >> 10, j = wid & 1023;
    const float* ar = attn + b * DD;
    const float* wr = Wo + (size_t)j * DD;
    float sum = 0.f;
    #pragma unroll
    for (int t = 0; t < 4; ++t) {
        float4 w4 = *(const float4*)(wr + t * 256 + lane * 4);
        float4 a4 = *(const float4*)(ar + t * 256 + lane * 4);
        sum = fmaf(a4.x, w4.x, sum);
        sum = fmaf(a4.y, w4.y, sum);
        sum = fmaf(a4.z, w4.z, sum);
        sum = fmaf(a4.w, w4.w, sum);
    }
    #pragma unroll
    for (int m = 32; m; m >>= 1) sum += __shfl_xor(sum, m);
    if (lane == 0)
        out[b * DD + j] = sum + bo[j];
}

extern "C" void kernel_launch(void* const* d_in, const int* in_sizes, int n_in,
                              void* d_out, int out_size, void* d_ws, size_t ws_size,
                              hipStream_t stream) {
    const float* x      = (const float*)d_in[0];
    const float* Wq     = (const float*)d_in[1];
    const float* bq     = (const float*)d_in[2];
    const float* Wk     = (const float*)d_in[3];
    const float* bk     = (const float*)d_in[4];
    const float* Wv     = (const float*)d_in[5];
    const float* bv     = (const float*)d_in[6];
    const float* Wo     = (const float*)d_in[7];
    const float* bo     = (const float*)d_in[8];
    const float* past_k = (const float*)d_in[9];
    const float* past_v = (const float*)d_in[10];
    float* out = (float*)d_out;

    float* qkv  = (float*)d_ws;                        // 3*8192 floats
    float* part = qkv + 3 * BB * DD;                   // 1024*66 floats
    float* attn = part + PAIRS * CHUNKS * PART_STRIDE; // 8192 floats

    qkv_kernel<<<3 * BB * DD / 4, 256, 0, stream>>>(x, Wq, bq, Wk, bk, Wv, bv, qkv);
    rope_kernel<<<16, 256, 0, stream>>>(qkv);
    attn_part_kernel<<<PAIRS * CHUNKS, 256, 0, stream>>>(past_k, past_v, qkv, part);
    attn_reduce_kernel<<<PAIRS, 64, 0, stream>>>(part, qkv, attn);
    oproj_kernel<<<BB * DD / 4, 256, 0, stream>>>(attn, Wo, bo, out);
}